// Round 19
// baseline (120.488 us; speedup 1.0000x reference)
//
#include <hip/hip_runtime.h>
#include <hip/hip_cooperative_groups.h>

namespace cg = cooperative_groups;

// ---------------------------------------------------------------------------
// FFT_Conv_Layer == 3x3 "same" spatial conv with flipped REAL filter plane:
//   out[b,o,y,x] = sum_{i,ky,kx} filts[0,i,o,ky,kx,0] * img[b,i,y+1-ky,x+1-kx]
//
// Ladder: R2 22.54 | R7 21.24 | R8 21.07 (champion) | R13 23.98 | R14 diag:
//   [K+store]=3.73us marginal, ~17us = prep_w+stage+2 launches+fixed.
// R18 (90us, FAILED): per-block register weight gather = 288 uncoalesced
//   scalar loads/lane x 2048 waves (MfmaUtil 1.9%) — gather must happen ONCE.
// R19: cooperative single launch. R8 structure verbatim (512 blk x 256 thr =
//   2 blk/CU, all co-resident), but prep_w's gather sharded 1 entry/thread
//   over the first 144 blocks, issued before staging (latency hides under the
//   stage burst) -> __threadfence -> grid.sync() -> K-loop (wf L2-hot).
//   Deletes one dispatch + serial prep_w time.
// ---------------------------------------------------------------------------

typedef _Float16 f16x8 __attribute__((ext_vector_type(8)));
typedef float    f32x4 __attribute__((ext_vector_type(4)));

#define NB 16
#define NC 64
#define NH 64
#define NW 64
#define CHUNKS 528                 // 66 xp positions * 8 channel-chunks per slab
#define SLAB_BYTES (CHUNKS * 16)   // 8448 B per image row slab
#define WF_HALFS (9 * 2 * 4 * 64 * 8)  // 36,864

// ---------------------------------------------------------------------------
// conv_coop: 512 blocks (XCD-swizzled) = (b, 2-row group), 4 waves (256 thr).
//   Phase A (pre-sync): [first 144 blocks] gather 1 wf entry/thread:
//     wf[f] = filts[(((kc*32+(l/16)*8+e)*64 + n*16+l%16)*9 + t)*2], f decoded
//     as in prep_w. All blocks: stage 4 slabs (R8 verbatim: 64 coalesced f32
//     loads/thread, cvt f16, 8 swizzled ds_write_b128; pads by l<16).
//   grid.sync() (cooperative; replaces the prep_w->conv kernel boundary).
//   Phase B: R8-verbatim K-loop: 4 A ds_reads + 2 B global (L2-hot wf) +
//     8 MFMA per step; coalesced f32x4 stores.
//   C/D layout (m89/m91-verified): o = n*16+(lane&15), x = m*16+(lane>>4)*4+j
// ---------------------------------------------------------------------------
__global__ __launch_bounds__(256, 2) void conv_coop(const float* __restrict__ imgs,
                                                    const float* __restrict__ filts,
                                                    _Float16* wf,
                                                    float* __restrict__ out) {
    __shared__ uint4 ldsb[4 * SLAB_BYTES / 16];   // 33,792 B
    char* lds = reinterpret_cast<char*>(ldsb);
    const int bid = blockIdx.x;
    const int swz = ((bid & 7) << 6) | (bid >> 3);   // bijective: 512 = 8*64
    const int b   = swz >> 5;
    const int y0  = (swz & 31) << 1;
    const int tid = threadIdx.x;
    const int w   = tid >> 6;
    const int l   = tid & 63;
    const int h   = l >> 4;
    const int r   = l & 15;

    // ---- phase A1: sharded weight gather (1 entry/thread, blocks 0..143) ----
    {
        const int f = bid * 256 + tid;           // unswizzled id; any bijection ok
        if (f < WF_HALFS) {
            const int e  = f & 7;
            const int fl = (f >> 3) & 63;
            const int n  = (f >> 9) & 3;
            const int kc = (f >> 11) & 1;
            const int t  = f >> 12;              // 0..8
            const int i  = kc * 32 + (fl >> 4) * 8 + e;
            const int o  = n * 16 + (fl & 15);
            const int ky = t / 3, kx = t % 3;
            wf[f] = (_Float16)filts[(((i * 64 + o) * 3 + ky) * 3 + kx) * 2];
        }
    }

    // ---- phase A2: stage slab w = image row y0 + w - 1 (R8 verbatim) ----
    {
        const int y  = y0 + w - 1;
        const bool yv = ((unsigned)y < (unsigned)NH);
        char* slab = lds + w * SLAB_BYTES;
        if (l < 16) {
            const int ci  = l >> 1;
            const int xp2 = (l & 1) ? 65 : 0;
            const int c2  = xp2 * 8 + (ci ^ (xp2 & 7));
            f16x8 z;
            #pragma unroll
            for (int k = 0; k < 8; ++k) z[k] = (_Float16)0.f;
            *reinterpret_cast<f16x8*>(slab + c2 * 16) = z;
        }
        float f[64];
        if (yv) {
            const float* src = imgs + (((size_t)(b * NC)) * NH + y) * NW + l;
            #pragma unroll
            for (int c = 0; c < 64; ++c) f[c] = src[(size_t)c * NH * NW];
        } else {
            #pragma unroll
            for (int c = 0; c < 64; ++c) f[c] = 0.f;
        }
        const int xp = l + 1;
        #pragma unroll
        for (int ci = 0; ci < 8; ++ci) {
            f16x8 v;
            #pragma unroll
            for (int k = 0; k < 8; ++k) v[k] = (_Float16)f[ci * 8 + k];
            const int chunk = xp * 8 + (ci ^ (xp & 7));
            *reinterpret_cast<f16x8*>(slab + chunk * 16) = v;
        }
    }

    __threadfence();                     // make wf stores device-visible
    cg::this_grid().sync();              // replaces the prep_w kernel boundary

    const int row = w >> 1;
    const int oh  = w & 1;

    f32x4 acc[4][2];
    #pragma unroll
    for (int m = 0; m < 4; ++m)
        #pragma unroll
        for (int n = 0; n < 2; ++n)
            acc[m][n] = f32x4{0.f, 0.f, 0.f, 0.f};

    #pragma unroll
    for (int ky = 0; ky < 3; ++ky) {
        const char* slab = lds + (row + 2 - ky) * SLAB_BYTES;
        #pragma unroll
        for (int kx = 0; kx < 3; ++kx) {
            const _Float16* wft = wf + (size_t)(ky * 3 + kx) * (2 * 4 * 64 * 8);
            #pragma unroll
            for (int kc = 0; kc < 2; ++kc) {
                f16x8 a[4], bb[2];
                #pragma unroll
                for (int m = 0; m < 4; ++m) {
                    const int xp = m * 16 + r + 2 - kx;
                    const int chunk = xp * 8 + (((kc << 2) + h) ^ (xp & 7));
                    a[m] = *reinterpret_cast<const f16x8*>(slab + chunk * 16);
                }
                #pragma unroll
                for (int n = 0; n < 2; ++n)
                    bb[n] = *reinterpret_cast<const f16x8*>(
                        wft + ((size_t)((kc << 2) + (oh * 2 + n)) * 64 + l) * 8);
                #pragma unroll
                for (int m = 0; m < 4; ++m)
                    #pragma unroll
                    for (int n = 0; n < 2; ++n)
                        acc[m][n] = __builtin_amdgcn_mfma_f32_16x16x32_f16(a[m], bb[n], acc[m][n], 0, 0, 0);
            }
        }
    }

    const int y = y0 + row;
    #pragma unroll
    for (int m = 0; m < 4; ++m) {
        const int x0 = m * 16 + h * 4;
        #pragma unroll
        for (int n = 0; n < 2; ++n) {
            const int o = oh * 32 + n * 16 + r;
            *reinterpret_cast<f32x4*>(out + (((size_t)(b * 64 + o) * 64 + y) * 64) + x0) = acc[m][n];
        }
    }
}

extern "C" void kernel_launch(void* const* d_in, const int* in_sizes, int n_in,
                              void* d_out, int out_size, void* d_ws, size_t ws_size,
                              hipStream_t stream) {
    const float* imgs  = (const float*)d_in[0];   // [16][64][64][64] f32
    const float* filts = (const float*)d_in[1];   // [1][64][64][3][3][2] f32
    float* out = (float*)d_out;                   // [16][64][64][64] f32
    _Float16* wfb = (_Float16*)d_ws;              // 73,728 B

    void* args[] = { (void*)&imgs, (void*)&filts, (void*)&wfb, (void*)&out };
    hipLaunchCooperativeKernel(reinterpret_cast<void*>(conv_coop),
                               dim3(NB * 32), dim3(256), args, 0, stream);
}

// Round 20
// 20.912 us; speedup vs baseline: 5.7617x; 5.7617x over previous
//
#include <hip/hip_runtime.h>

// ---------------------------------------------------------------------------
// FFT_Conv_Layer == 3x3 "same" spatial conv with flipped REAL filter plane:
//   out[b,o,y,x] = sum_{i,ky,kx} filts[0,i,o,ky,kx,0] * img[b,i,y+1-ky,x+1-kx]
//
// Ladder: R8 21.07 (champion) | R14 diag: marginal [K+store]=3.73us, K-phase
//   binding pipe = LDS issue (2.9us/CU) | R18 fused gather 90us (uncoalesced)
//   | R19 coop grid.sync 120us. Fills between replays evict L3 -> stage reads
//   are HBM every replay (traffic is real money, ~6.2 GB/us marginal).
// R20: champion + two compatible levers, occupancy pinned at 2 waves/SIMD:
//   (1) wave retile 64x32 -> 32x64: a[2]+bb[4] per step halves A ds_reads
//       (LDS 2.9 -> 1.45us/CU), B-loads ride the idle VMEM pipe (L2-hot wf).
//   (2) 4-row blocks (256 x 512thr, 6 slabs): staged reads 33.6 -> 25.2 MB.
// ---------------------------------------------------------------------------

typedef _Float16 f16x8 __attribute__((ext_vector_type(8)));
typedef float    f32x4 __attribute__((ext_vector_type(4)));

#define NB 16
#define NC 64
#define NH 64
#define NW 64
#define CHUNKS 528                 // 66 xp positions * 8 channel-chunks per slab
#define SLAB_BYTES (CHUNKS * 16)   // 8448 B per image row slab
#define WF_HALFS (9 * 2 * 4 * 64 * 8)  // 36,864

// ---------------------------------------------------------------------------
// prep_w: filts [1][inC][outC][3][3][2] f32 -> per-fragment f16 weights
//   Wf[t][kc][n][lane][e] = filts[0][ i=kc*32+(l/16)*8+e ][ o=n*16+l%16 ][ky][kx][0]
// ---------------------------------------------------------------------------
__global__ __launch_bounds__(256) void prep_w(const float* __restrict__ filts,
                                              _Float16* __restrict__ wf) {
    const int f = blockIdx.x * 256 + threadIdx.x;
    if (f >= WF_HALFS) return;
    const int e  = f & 7;
    const int l  = (f >> 3) & 63;
    const int n  = (f >> 9) & 3;
    const int kc = (f >> 11) & 1;
    const int t  = f >> 12;              // 0..8
    const int i  = kc * 32 + (l >> 4) * 8 + e;
    const int o  = n * 16 + (l & 15);
    const int ky = t / 3, kx = t % 3;
    wf[f] = (_Float16)filts[(((i * 64 + o) * 3 + ky) * 3 + kx) * 2];
}

// ---------------------------------------------------------------------------
// conv_direct: 256 blocks (XCD-swizzled) = (b, 4-row quad), 8 waves (512 thr).
//   LDS: 6 slabs = image rows y0-1 .. y0+4 (50,688 B; 1 blk/CU, 2 waves/SIMD).
//   Staging: 48 jobs (slab = j/8, chunk ci = j%8), wave w takes j = w+8k:
//     8 coalesced f32 loads at x=lane, cvt f16, one swizzled ds_write_b128
//     (chunk = xp*8 + (ci^(xp&7))). Pads: tid<96 zero xp=0,65 chunks.
//   Compute: wave w = (row w>>1, xh w&1) owns 32x x 64o: 2m x 4n frags.
//     Per (ky,kx,kc): 2 A ds_reads + 4 B global (L2-hot wf) + 8 MFMA.
//   C/D layout (m89/m91-verified): o = n*16+(lane&15), x = m*16+(lane>>4)*4+j
// ---------------------------------------------------------------------------
__global__ __launch_bounds__(512, 1) void conv_direct(const float* __restrict__ imgs,
                                                      const _Float16* __restrict__ wf,
                                                      float* __restrict__ out) {
    __shared__ char lds[6 * SLAB_BYTES];   // 50,688 B
    const int bid = blockIdx.x;
    const int swz = ((bid & 7) << 5) | (bid >> 3);   // bijective: 256 = 8*32
    const int b   = swz >> 4;
    const int y0  = (swz & 15) << 2;     // first of 4 output rows
    const int tid = threadIdx.x;
    const int w   = tid >> 6;            // wave 0..7
    const int l   = tid & 63;
    const int h   = l >> 4;              // k-chunk lane group
    const int r   = l & 15;              // A-row / B-col within fragment

    // ---- zero pads: 6 slabs x 16 chunks (xp = 0, 65) ----
    if (tid < 96) {
        const int sl  = tid >> 4;
        const int rem = tid & 15;
        const int ci  = rem >> 1;
        const int xp2 = (rem & 1) ? 65 : 0;
        const int c2  = xp2 * 8 + (ci ^ (xp2 & 7));
        f16x8 z;
        #pragma unroll
        for (int k = 0; k < 8; ++k) z[k] = (_Float16)0.f;
        *reinterpret_cast<f16x8*>(lds + sl * SLAB_BYTES + c2 * 16) = z;
    }

    // ---- stage 6 slabs (image rows y0-1 .. y0+4), 48 jobs over 8 waves ----
    #pragma unroll
    for (int j = 0; j < 6; ++j) {
        const int job = w + j * 8;
        const int sl  = job >> 3;        // slab 0..5
        const int ci  = job & 7;         // channel chunk
        const int yy  = y0 - 1 + sl;
        float fr[8];
        if ((unsigned)yy < (unsigned)NH) {
            const float* src = imgs + (((size_t)(b * NC + ci * 8)) * NH + yy) * NW + l;
            #pragma unroll
            for (int k = 0; k < 8; ++k) fr[k] = src[(size_t)k * NH * NW];
        } else {
            #pragma unroll
            for (int k = 0; k < 8; ++k) fr[k] = 0.f;
        }
        f16x8 v;
        #pragma unroll
        for (int k = 0; k < 8; ++k) v[k] = (_Float16)fr[k];
        const int xp = l + 1;            // lane covers x = l
        const int chunk = xp * 8 + (ci ^ (xp & 7));
        *reinterpret_cast<f16x8*>(lds + sl * SLAB_BYTES + chunk * 16) = v;
    }
    __syncthreads();

    const int row = w >> 1;              // output row within quad (0..3)
    const int xh  = w & 1;               // x half (0..1)

    f32x4 acc[2][4];
    #pragma unroll
    for (int m = 0; m < 2; ++m)
        #pragma unroll
        for (int n = 0; n < 4; ++n)
            acc[m][n] = f32x4{0.f, 0.f, 0.f, 0.f};

    #pragma unroll
    for (int ky = 0; ky < 3; ++ky) {
        const char* slab = lds + (row + 2 - ky) * SLAB_BYTES;   // sl in 0..5
        #pragma unroll
        for (int kx = 0; kx < 3; ++kx) {
            const _Float16* wft = wf + (size_t)(ky * 3 + kx) * (2 * 4 * 64 * 8);
            #pragma unroll
            for (int kc = 0; kc < 2; ++kc) {
                f16x8 a[2], bb[4];
                #pragma unroll
                for (int m = 0; m < 2; ++m) {
                    const int xp = xh * 32 + m * 16 + r + 2 - kx;  // 0..65
                    const int chunk = xp * 8 + (((kc << 2) + h) ^ (xp & 7));
                    a[m] = *reinterpret_cast<const f16x8*>(slab + chunk * 16);
                }
                #pragma unroll
                for (int n = 0; n < 4; ++n)
                    bb[n] = *reinterpret_cast<const f16x8*>(
                        wft + ((size_t)((kc << 2) + n) * 64 + l) * 8);
                #pragma unroll
                for (int m = 0; m < 2; ++m)
                    #pragma unroll
                    for (int n = 0; n < 4; ++n)
                        acc[m][n] = __builtin_amdgcn_mfma_f32_16x16x32_f16(a[m], bb[n], acc[m][n], 0, 0, 0);
            }
        }
    }

    const int y = y0 + row;
    #pragma unroll
    for (int m = 0; m < 2; ++m) {
        const int x0 = xh * 32 + m * 16 + h * 4;
        #pragma unroll
        for (int n = 0; n < 4; ++n) {
            const int o = n * 16 + r;
            *reinterpret_cast<f32x4*>(out + (((size_t)(b * 64 + o) * 64 + y) * 64) + x0) = acc[m][n];
        }
    }
}

extern "C" void kernel_launch(void* const* d_in, const int* in_sizes, int n_in,
                              void* d_out, int out_size, void* d_ws, size_t ws_size,
                              hipStream_t stream) {
    const float* imgs  = (const float*)d_in[0];   // [16][64][64][64] f32
    const float* filts = (const float*)d_in[1];   // [1][64][64][3][3][2] f32
    float* out = (float*)d_out;                   // [16][64][64][64] f32
    _Float16* wfb = (_Float16*)d_ws;              // 73,728 B only

    hipLaunchKernelGGL(prep_w, dim3((WF_HALFS + 255) / 256), dim3(256), 0, stream, filts, wfb);
    hipLaunchKernelGGL(conv_direct, dim3(256), dim3(512), 0, stream, imgs, wfb, out);
}